// Round 6
// baseline (339.778 us; speedup 1.0000x reference)
//
#include <hip/hip_runtime.h>
#include <hip/hip_fp16.h>
#include <cstddef>
#include <cstdint>

#define N_PTS 16384
#define K_PTS 1024
#define D_DIM 512
#define EPS_F 0.1f
#define ITERS 20
#define MU_F (1.0f/16384.0f)
#define NU_F (1.0f/1024.0f)
#define NCOPY 8
#define SINK_BLOCKS 256
#define FLAG_STRIDE 16   // 64B padding per flag
#define ACC_TOTAL ((ITERS + 1) * NCOPY * K_PTS)

// workspace: proven footprint only (~0.70 MB)
#define WS_ACCUM_BYTES ((size_t)ACC_TOTAL * 4)                    // 688128
#define WS_FLAGS_BYTES ((size_t)SINK_BLOCKS * FLAG_STRIDE * 4)    // 16384

// d_out layout (64 MiB + 4 B):
//   [0, 64 MiB)       T (final output)
//   [32 MiB, 48 MiB)  Xf16   } written by convert, read only in fused phase 1,
//   [48 MiB, 49 MiB)  Pf16   } clobbered by T only after 21 global flag barriers
//   [49 MiB, ...)     xn, pn (f32 norms)
//   [64 MiB]          loss

typedef float f32x4 __attribute__((ext_vector_type(4)));
typedef _Float16 f16x8 __attribute__((ext_vector_type(8)));

__device__ __forceinline__ float wave_reduce_sum(float s) {
#pragma unroll
  for (int off = 32; off > 0; off >>= 1) s += __shfl_xor(s, off, 64);
  return s;
}
__device__ __forceinline__ float wave_reduce_max(float s) {
#pragma unroll
  for (int off = 32; off > 0; off >>= 1) s = fmaxf(s, __shfl_xor(s, off, 64));
  return s;
}

// async 16B global->LDS (linear LDS dest: wave-uniform base + lane*16)
__device__ __forceinline__ void gl16(const void* g, void* l) {
  __builtin_amdgcn_global_load_lds(
      (const __attribute__((address_space(1))) unsigned int*)g,
      (__attribute__((address_space(3))) unsigned int*)l, 16, 0, 0);
}

// ---------------------------------------------------------------- init
__global__ __launch_bounds__(256) void init_kernel(float* __restrict__ accum,
                                                   unsigned int* __restrict__ flags,
                                                   unsigned int* __restrict__ maxbits,
                                                   float* __restrict__ loss) {
  int i = blockIdx.x * 256 + threadIdx.x;
  if (i < ACC_TOTAL) accum[i] = 0.0f;
  if (i < SINK_BLOCKS * FLAG_STRIDE) flags[i] = 0u;
  if (i == 0) { *maxbits = 0u; *loss = 0.0f; }
}

// ---------------------------------------------------------------- convert pass (unchanged, proven)
__global__ __launch_bounds__(256) void convert_kernel(const float* __restrict__ X,
                                                      const float* __restrict__ P,
                                                      unsigned short* __restrict__ Xf,
                                                      unsigned short* __restrict__ Pf,
                                                      float* __restrict__ xn,
                                                      float* __restrict__ pn) {
  const int gw = (blockIdx.x * 256 + threadIdx.x) >> 6;
  const int lane = threadIdx.x & 63;

  const float* src;
  unsigned short* dst;
  float* nrm;
  if (gw < N_PTS) {
    src = X + (size_t)gw * D_DIM;
    dst = Xf + (size_t)gw * D_DIM;
    nrm = xn + gw;
  } else {
    int r = gw - N_PTS;
    src = P + (size_t)r * D_DIM;
    dst = Pf + (size_t)r * D_DIM;
    nrm = pn + r;
  }

  float4 f0 = *(const float4*)(src + lane * 8);
  float4 f1 = *(const float4*)(src + lane * 8 + 4);
  float f[8] = {f0.x, f0.y, f0.z, f0.w, f1.x, f1.y, f1.z, f1.w};

  float s = 0.f;
#pragma unroll
  for (int j = 0; j < 8; j++) s += f[j] * f[j];

  unsigned int u[4];
#pragma unroll
  for (int j = 0; j < 4; j++) {
    unsigned int lo = (unsigned int)__half_as_ushort(__float2half(f[2 * j]));
    unsigned int hi = (unsigned int)__half_as_ushort(__float2half(f[2 * j + 1]));
    u[j] = lo | (hi << 16);
  }
  *(uint4*)(dst + lane * 8) = make_uint4(u[0], u[1], u[2], u[3]);

  s = wave_reduce_sum(s);
  if (lane == 0) *nrm = s;
}

// ---------------------------------------------------------------- fused GEMM + Sinkhorn
// 256 persistent blocks x 512 threads (1 block/CU, as the proven flag protocol
// already requires). Phase 1: block builds its 64x1024 C-slab via f16 MFMA:
// X slab (64KB) resident in LDS; P streamed in 32-col panels through a SINGLE
// 32KB LDS buffer with REGISTER prefetch (T14 split: global->reg issued before
// the MFMA phase, reg->LDS swizzled ds_write after the barrier that drains the
// previous panel's reads). Per-panel 4KB LDS transpose redistributes MFMA
// fragments into the k4 register layout, rounding through fp16 exactly like
// the old Ch path. One extra flags-round publishes the global C max, then
// K=exp(C*factor) in-register and the VERIFIED iteration loop runs verbatim
// (flag values shifted +1). Total LDS ~104.4 KB (<=128 KB proven envelope).
__global__ __launch_bounds__(512, 2) void fused_kernel(
    const unsigned short* __restrict__ Xf,
    const unsigned short* __restrict__ Pf,
    const float* __restrict__ xn,
    const float* __restrict__ pn,
    unsigned int* __restrict__ maxbits,
    float* __restrict__ accum,          // (ITERS+1) x NCOPY x K_PTS
    unsigned int* __restrict__ flags,   // SINK_BLOCKS x FLAG_STRIDE
    float* __restrict__ T,
    float* __restrict__ loss) {
  __shared__ __align__(16) char smem[98304];               // X[64KB] | Pbuf[32KB]
  __shared__ __align__(16) unsigned short t_lds[64 * 33];  // per-panel transpose tile
  __shared__ float xn_s[64];
  __shared__ float pn_s[K_PTS];
  __shared__ float wred[8];

  unsigned short* X_lds = (unsigned short*)smem;           // [64][512] halfs
  unsigned short* Pbuf = (unsigned short*)(smem + 65536);  // [32][512] halfs

  const int tid = threadIdx.x;
  const int lane = tid & 63, wv = tid >> 6;
  const int b = blockIdx.x;
  const int rb0 = b * 64;            // block's first row
  const int r0 = rb0 + wv * 8;       // wave's first owned row (phase-2 layout)

  // ---------------- phase 1: C-slab via MFMA ----------------
  if (tid < 64) xn_s[tid] = xn[rb0 + tid];
  pn_s[tid] = pn[tid];
  pn_s[tid + 512] = pn[tid + 512];

  // gl16 staging swizzle: LDS slot l holds source granule (l&~7)|((l&7)^(row&7));
  // each wave loads rows with row&7 == wv&7, one 1024B row per gl16.
  const int gsw = (lane & ~7) | ((lane & 7) ^ (wv & 7));
#pragma unroll
  for (int q = 0; q < 8; q++) {
    int row = q * 8 + wv;
    gl16((const char*)Xf + (size_t)(rb0 + row) * 1024 + gsw * 16, X_lds + row * 512);
  }
#pragma unroll
  for (int q = 0; q < 4; q++) {
    int row = q * 8 + wv;
    gl16((const char*)Pf + (size_t)row * 1024 + gsw * 16, Pbuf + row * 512);
  }
  __syncthreads();   // X + panel 0 resident (vmcnt drained at barrier)

  // register-prefetch geometry: thread t handles panel row t>>4, granules (t&15)+16j
  const int prow = tid >> 4;          // 0..31
  const int pgl = tid & 15;

  const int rt = wv >> 1, ct = wv & 1;     // wave's row-tile (0..3), col-tile (0..1)
  const int fr = lane & 15, fg = lane >> 4;
  float lmax = -3.4e38f;
  f32x4 k4[32];      // raw C (f16-rounded) until cmax round, then exp'd in place

#pragma unroll
  for (int p = 0; p < 32; p++) {
    // issue next panel's global loads early (latency hides under MFMA + barrier)
    uint4 pref[4];
    if (p < 31) {
      const char* srcrow = (const char*)Pf + (size_t)((p + 1) * 32 + prow) * 1024;
#pragma unroll
      for (int j = 0; j < 4; j++)
        pref[j] = *(const uint4*)(srcrow + (pgl + 16 * j) * 16);
    }

    f32x4 acc = {};
#pragma unroll
    for (int kk = 0; kk < 16; kk++) {
      int kg = kk * 4 + fg;
      int slot = (kg & ~7) | ((kg & 7) ^ (fr & 7));
      f16x8 av = *(const f16x8*)&X_lds[(rt * 16 + fr) * 512 + slot * 8];
      f16x8 bv = *(const f16x8*)&Pbuf[(ct * 16 + fr) * 512 + slot * 8];
      acc = __builtin_amdgcn_mfma_f32_16x16x32_f16(av, bv, acc, 0, 0, 0);
    }
    {  // tile epilogue: C/D layout col=lane&15, row=(lane>>4)*4+reg
      int colL = ct * 16 + fr;
      float pnc = pn_s[p * 32 + colL];
#pragma unroll
      for (int r = 0; r < 4; r++) {
        int rowL = rt * 16 + fg * 4 + r;
        float val = xn_s[rowL] + pnc - 2.0f * acc[r];
        lmax = fmaxf(lmax, val);   // f32 max before fp16 rounding (matches Ch path)
        t_lds[rowL * 33 + colL] = __half_as_ushort(__float2half(val));
      }
    }
    __syncthreads();   // B1: t_lds complete AND all Pbuf reads of panel p drained

    // commit prefetched panel p+1 into Pbuf (swizzled write = same involution as read)
    if (p < 31) {
#pragma unroll
      for (int j = 0; j < 4; j++) {
        int g = pgl + 16 * j;
        int slot = (g & ~7) | ((g & 7) ^ (prow & 7));
        *(uint4*)&Pbuf[prow * 512 + slot * 8] = pref[j];
      }
    }
    // extraction: cols [32p,32p+32) belong to lanes with lane>>5 == p&1,
    // k4 slot q=p>>3, e=(p>>1)&3 (all static under unroll)
    if ((lane >> 5) == (p & 1)) {
#pragma unroll
      for (int i = 0; i < 8; i++)
        k4[i * 4 + (p >> 3)][(p >> 1) & 3] =
            __half2float(__ushort_as_half(t_lds[(wv * 8 + i) * 33 + (lane & 31)]));
    }
    __syncthreads();   // B2: t_lds reusable + Pbuf write visible for next panel
  }

  // ---------------- global C-max round (flag value 1) ----------------
  lmax = wave_reduce_max(lmax);
  if (lane == 0) wred[wv] = lmax;
  __syncthreads();
  if (tid == 0) {
    float m = wred[0];
#pragma unroll
    for (int i = 1; i < 8; i++) m = fmaxf(m, wred[i]);
    atomicMax((int*)maxbits, __float_as_int(m));  // global max is positive
    __hip_atomic_store(&flags[(size_t)b * FLAG_STRIDE], 1u,
                       __ATOMIC_RELEASE, __HIP_MEMORY_SCOPE_AGENT);
  }
  if (tid < SINK_BLOCKS) {
    while (__hip_atomic_load(&flags[(size_t)tid * FLAG_STRIDE],
                             __ATOMIC_RELAXED, __HIP_MEMORY_SCOPE_AGENT) < 1u)
      __builtin_amdgcn_s_sleep(4);
  }
  __syncthreads();
  float factor;
  {
    float cmax = __uint_as_float(__hip_atomic_load(maxbits, __ATOMIC_RELAXED,
                                                   __HIP_MEMORY_SCOPE_AGENT));
    factor = -1.0f / ((cmax + 1e-8f) * EPS_F);
  }
#pragma unroll
  for (int j = 0; j < 32; j++)
#pragma unroll
    for (int e = 0; e < 4; e++)
      k4[j][e] = __expf(k4[j][e] * factor);

  // ---------------- phase 2: verified Sinkhorn loop (LDS aliases X region) ----------------
  float* v_lds = (float*)smem;                       // 4 KB
  float (*red)[K_PTS] = (float (*)[K_PTS])(smem + 4096);  // 8 x 4 KB
  v_lds[tid * 2 + 0] = 1.0f;
  v_lds[tid * 2 + 1] = 1.0f;
  __syncthreads();

  float su[8];
  for (int t = 0; t < ITERS; t++) {
    f32x4 vr4[4];
#pragma unroll
    for (int q = 0; q < 4; q++)
#pragma unroll
      for (int e = 0; e < 4; e++)
        vr4[q][e] = v_lds[(4 * q + e) * 64 + lane];

    float s[8];
#pragma unroll
    for (int i = 0; i < 8; i++) {
      f32x4 d = k4[i * 4 + 0] * vr4[0] + k4[i * 4 + 1] * vr4[1]
              + k4[i * 4 + 2] * vr4[2] + k4[i * 4 + 3] * vr4[3];
      s[i] = d[0] + d[1] + d[2] + d[3];
    }
    {
      const bool h32 = (lane & 32) != 0;
      float a[4];
#pragma unroll
      for (int i = 0; i < 4; i++) {
        float x = h32 ? s[i] : s[i + 4];
        float y = h32 ? s[i + 4] : s[i];
        a[i] = y + __shfl_xor(x, 32, 64);
      }
      const bool h16 = (lane & 16) != 0;
      float c[2];
#pragma unroll
      for (int i = 0; i < 2; i++) {
        float x = h16 ? a[i] : a[i + 2];
        float y = h16 ? a[i + 2] : a[i];
        c[i] = y + __shfl_xor(x, 16, 64);
      }
      const bool h8 = (lane & 8) != 0;
      float x = h8 ? c[0] : c[1];
      float y = h8 ? c[1] : c[0];
      float w = y + __shfl_xor(x, 8, 64);
      w += __shfl_xor(w, 4, 64);
      w += __shfl_xor(w, 2, 64);
      w += __shfl_xor(w, 1, 64);
      float ui_local = MU_F / (w + 1e-8f);
#pragma unroll
      for (int i = 0; i < 8; i++)
        su[i] = __uint_as_float(__builtin_amdgcn_readlane(__float_as_uint(ui_local), i * 8));
    }
    f32x4 ca4[4] = {};
#pragma unroll
    for (int i = 0; i < 8; i++)
#pragma unroll
      for (int q = 0; q < 4; q++)
        ca4[q] += su[i] * k4[i * 4 + q];

    __syncthreads();
#pragma unroll
    for (int q = 0; q < 4; q++)
#pragma unroll
      for (int e = 0; e < 4; e++)
        red[wv][(4 * q + e) * 64 + lane] = ca4[q][e];
    __syncthreads();
    {
      float s0 = 0.f, s1 = 0.f;
#pragma unroll
      for (int w8 = 0; w8 < 8; w8++) {
        float2 v2 = *(const float2*)&red[w8][tid * 2];
        s0 += v2.x; s1 += v2.y;
      }
      float* dst = accum + (size_t)(t + 1) * (NCOPY * K_PTS)
                 + (size_t)(b & (NCOPY - 1)) * K_PTS + tid * 2;
      atomicAdd(dst + 0, s0);
      atomicAdd(dst + 1, s1);
    }
    __syncthreads();
    if (tid == 0)
      __hip_atomic_store(&flags[(size_t)b * FLAG_STRIDE], (unsigned)(t + 2),
                         __ATOMIC_RELEASE, __HIP_MEMORY_SCOPE_AGENT);
    if (tid < SINK_BLOCKS) {
      while (__hip_atomic_load(&flags[(size_t)tid * FLAG_STRIDE],
                               __ATOMIC_RELAXED, __HIP_MEMORY_SCOPE_AGENT) < (unsigned)(t + 2))
        __builtin_amdgcn_s_sleep(4);
    }
    __syncthreads();
    {
      float* st = accum + (size_t)(t + 1) * (NCOPY * K_PTS);
      float s0 = 0.f, s1 = 0.f;
#pragma unroll
      for (int c = 0; c < NCOPY; c++) {  // agent-scope loads bypass stale caches (G16)
        s0 += __hip_atomic_load(st + (size_t)c * K_PTS + tid * 2 + 0,
                                __ATOMIC_RELAXED, __HIP_MEMORY_SCOPE_AGENT);
        s1 += __hip_atomic_load(st + (size_t)c * K_PTS + tid * 2 + 1,
                                __ATOMIC_RELAXED, __HIP_MEMORY_SCOPE_AGENT);
      }
      v_lds[tid * 2 + 0] = NU_F / (s0 + 1e-8f);
      v_lds[tid * 2 + 1] = NU_F / (s1 + 1e-8f);
    }
    __syncthreads();
  }

  // final: T = u*k*v from registers; loss = sum(T * (-eps*ln k)).
  float lsum = 0.f;
#pragma unroll
  for (int i = 0; i < 8; i++) {
    float* Trow = T + (size_t)(r0 + i) * K_PTS + lane;
#pragma unroll
    for (int q = 0; q < 4; q++) {
#pragma unroll
      for (int e = 0; e < 4; e++) {
        int c = (4 * q + e) * 64;
        float kk = k4[i * 4 + q][e];
        float tv = su[i] * kk * v_lds[c + lane];
        Trow[c] = tv;
        lsum += tv * (-EPS_F * __logf(kk));
      }
    }
  }
  lsum = wave_reduce_sum(lsum);
  __syncthreads();
  if (lane == 0) wred[wv] = lsum;
  __syncthreads();
  if (tid == 0) {
    float m = 0.f;
#pragma unroll
    for (int i = 0; i < 8; i++) m += wred[i];
    atomicAdd(loss, m);
  }
}

// ---------------------------------------------------------------- launcher
extern "C" void kernel_launch(void* const* d_in, const int* in_sizes, int n_in,
                              void* d_out, int out_size, void* d_ws, size_t ws_size,
                              hipStream_t stream) {
  const float* x = (const float*)d_in[0];
  const float* p = (const float*)d_in[1];
  float* T = (float*)d_out;
  float* loss = (float*)d_out + (size_t)N_PTS * K_PTS;

  // f16 operands + norms in d_out's upper half (clobbered only by final T writes,
  // which sit after 21 global flag barriers — all operand reads precede barrier 1)
  unsigned short* Xf = (unsigned short*)((char*)d_out + ((size_t)32 << 20));
  unsigned short* Pf = (unsigned short*)((char*)d_out + ((size_t)48 << 20));
  float* xn = (float*)((char*)d_out + ((size_t)49 << 20));
  float* pn = xn + N_PTS;

  char* wsb = (char*)d_ws;
  float* accum = (float*)wsb;
  unsigned int* flags = (unsigned int*)(wsb + WS_ACCUM_BYTES);
  unsigned int* maxbits = (unsigned int*)(wsb + WS_ACCUM_BYTES + WS_FLAGS_BYTES);

  init_kernel<<<(ACC_TOTAL + 255) / 256, 256, 0, stream>>>(accum, flags, maxbits, loss);
  convert_kernel<<<(N_PTS + K_PTS) / 4, 256, 0, stream>>>(x, p, Xf, Pf, xn, pn);
  fused_kernel<<<SINK_BLOCKS, 512, 0, stream>>>(Xf, Pf, xn, pn, maxbits, accum, flags, T, loss);
}

// Round 7
// 337.964 us; speedup vs baseline: 1.0054x; 1.0054x over previous
//
#include <hip/hip_runtime.h>
#include <hip/hip_fp16.h>
#include <cstddef>
#include <cstdint>

#define N_PTS 16384
#define K_PTS 1024
#define D_DIM 512
#define EPS_F 0.1f
#define ITERS 20
#define MU_F (1.0f/16384.0f)
#define NU_F (1.0f/1024.0f)
#define NCOPY 8
#define SINK_BLOCKS 256
#define FLAG_STRIDE 16   // 64B padding per flag
#define ACC_TOTAL ((ITERS + 1) * NCOPY * K_PTS)

// workspace: proven footprint only (~0.70 MB)
#define WS_ACCUM_BYTES ((size_t)ACC_TOTAL * 4)                    // 688128
#define WS_FLAGS_BYTES ((size_t)SINK_BLOCKS * FLAG_STRIDE * 4)    // 16384

// d_out layout (64 MiB + 4 B):
//   [0, 64 MiB)       T (final output)
//   [48 MiB, 49 MiB)  Pf16  } written by convert_p, read only in fused phase 1,
//   [49 MiB, +4 KiB)  pn    } clobbered by T only after 21 global flag barriers
//   [64 MiB]          loss
// (Xf is GONE: X is read as f32 directly inside the fused kernel, once chip-wide.)

typedef float f32x4 __attribute__((ext_vector_type(4)));
typedef _Float16 f16x8 __attribute__((ext_vector_type(8)));

__device__ __forceinline__ float wave_reduce_sum(float s) {
#pragma unroll
  for (int off = 32; off > 0; off >>= 1) s += __shfl_xor(s, off, 64);
  return s;
}
__device__ __forceinline__ float wave_reduce_max(float s) {
#pragma unroll
  for (int off = 32; off > 0; off >>= 1) s = fmaxf(s, __shfl_xor(s, off, 64));
  return s;
}

// async 16B global->LDS (linear LDS dest: wave-uniform base + lane*16)
__device__ __forceinline__ void gl16(const void* g, void* l) {
  __builtin_amdgcn_global_load_lds(
      (const __attribute__((address_space(1))) unsigned int*)g,
      (__attribute__((address_space(3))) unsigned int*)l, 16, 0, 0);
}

// ---------------------------------------------------------------- init
__global__ __launch_bounds__(256) void init_kernel(float* __restrict__ accum,
                                                   unsigned int* __restrict__ flags,
                                                   unsigned int* __restrict__ maxbits,
                                                   float* __restrict__ loss) {
  int i = blockIdx.x * 256 + threadIdx.x;
  if (i < ACC_TOTAL) accum[i] = 0.0f;
  if (i < SINK_BLOCKS * FLAG_STRIDE) flags[i] = 0u;
  if (i == 0) { *maxbits = 0u; *loss = 0.0f; }
}

// ---------------------------------------------------------------- convert P only (3 MB total)
// fp32 -> f16 (RTN) + exact-f32 row sum-of-squares. One wave per row.
__global__ __launch_bounds__(256) void convert_p_kernel(const float* __restrict__ P,
                                                        unsigned short* __restrict__ Pf,
                                                        float* __restrict__ pn) {
  const int gw = (blockIdx.x * 256 + threadIdx.x) >> 6;  // row id 0..1023
  const int lane = threadIdx.x & 63;

  const float* src = P + (size_t)gw * D_DIM;
  unsigned short* dst = Pf + (size_t)gw * D_DIM;

  float4 f0 = *(const float4*)(src + lane * 8);
  float4 f1 = *(const float4*)(src + lane * 8 + 4);
  float f[8] = {f0.x, f0.y, f0.z, f0.w, f1.x, f1.y, f1.z, f1.w};

  float s = 0.f;
#pragma unroll
  for (int j = 0; j < 8; j++) s += f[j] * f[j];

  unsigned int u[4];
#pragma unroll
  for (int j = 0; j < 4; j++) {
    unsigned int lo = (unsigned int)__half_as_ushort(__float2half(f[2 * j]));
    unsigned int hi = (unsigned int)__half_as_ushort(__float2half(f[2 * j + 1]));
    u[j] = lo | (hi << 16);
  }
  *(uint4*)(dst + lane * 8) = make_uint4(u[0], u[1], u[2], u[3]);

  s = wave_reduce_sum(s);
  if (lane == 0) pn[gw] = s;
}

// ---------------------------------------------------------------- fused convert-X + GEMM + Sinkhorn
// 256 persistent blocks x 512 threads (1 block/CU). Phase 1a: block reads its
// OWN 64x512 f32 X-slab directly (X read once chip-wide), computes xn locally
// (bit-identical reduce tree), converts to f16 and swizzle-writes X_lds.
// Phase 1b: P streamed in 32-col f16 panels through a single 32KB buffer with
// register prefetch (r6-proven); per-panel transpose tile t_lds at stride 36
// halfs (conflict-free: banks 8*fg + (fr>>1) cover all 32, 2-way only).
// One flags-round publishes global C max; phase 2 = verified loop verbatim.
// Declared LDS 107.3 KB (= r6's proven envelope; +33KB HW overhead < 160KB).
__global__ __launch_bounds__(512, 2) void fused_kernel(
    const float* __restrict__ X,
    const unsigned short* __restrict__ Pf,
    const float* __restrict__ pn,
    unsigned int* __restrict__ maxbits,
    float* __restrict__ accum,          // (ITERS+1) x NCOPY x K_PTS
    unsigned int* __restrict__ flags,   // SINK_BLOCKS x FLAG_STRIDE
    float* __restrict__ T,
    float* __restrict__ loss) {
  __shared__ __align__(16) char smem[98304];               // X_lds[64KB] | Pbuf[32KB]
  __shared__ __align__(16) unsigned short t_lds[64 * 36];  // transpose tile, stride 36
  __shared__ float xn_s[64];
  __shared__ float pn_s[K_PTS];
  __shared__ float wred[8];

  unsigned short* X_lds = (unsigned short*)smem;           // [64][512] halfs, granule-swizzled
  unsigned short* Pbuf = (unsigned short*)(smem + 65536);  // [32][512] halfs

  const int tid = threadIdx.x;
  const int lane = tid & 63, wv = tid >> 6;
  const int b = blockIdx.x;
  const int rb0 = b * 64;            // block's first row
  const int r0 = rb0 + wv * 8;       // wave's first owned row (phase-2 layout)

  // ---------------- phase 1a: P panel 0 (async) + X slab staging ----------------
  // gl16 staging swizzle: LDS slot l holds source granule (l&~7)|((l&7)^(row&7)).
  const int gsw = (lane & ~7) | ((lane & 7) ^ (wv & 7));
#pragma unroll
  for (int q = 0; q < 4; q++) {
    int row = q * 8 + wv;            // row&7 == wv
    gl16((const char*)Pf + (size_t)row * 1024 + gsw * 16, Pbuf + row * 512);
  }
  // X: wave wv owns rows wv*8+i (same as phase-2); lane handles 8 consecutive floats.
#pragma unroll
  for (int i = 0; i < 8; i++) {
    const int r = wv * 8 + i;                       // r&7 == i
    const float* src = X + (size_t)(rb0 + r) * D_DIM + lane * 8;
    float4 f0 = *(const float4*)(src);
    float4 f1 = *(const float4*)(src + 4);
    float f[8] = {f0.x, f0.y, f0.z, f0.w, f1.x, f1.y, f1.z, f1.w};
    float s = 0.f;
#pragma unroll
    for (int j = 0; j < 8; j++) s += f[j] * f[j];
    unsigned int u[4];
#pragma unroll
    for (int j = 0; j < 4; j++) {
      unsigned int lo = (unsigned int)__half_as_ushort(__float2half(f[2 * j]));
      unsigned int hi = (unsigned int)__half_as_ushort(__float2half(f[2 * j + 1]));
      u[j] = lo | (hi << 16);
    }
    // lane's 8 halfs form source granule g=lane; write to swizzled slot (rule #21 pair
    // with the MFMA read path's slot formula).
    const int slot = (lane & ~7) | ((lane & 7) ^ i);
    *(uint4*)&X_lds[r * 512 + slot * 8] = make_uint4(u[0], u[1], u[2], u[3]);
    s = wave_reduce_sum(s);
    if (lane == 0) xn_s[r] = s;
  }
  pn_s[tid] = pn[tid];
  pn_s[tid + 512] = pn[tid + 512];
  __syncthreads();   // X_lds visible + P panel 0 drained (vmcnt at barrier)

  // ---------------- phase 1b: 32 P panels ----------------
  // register-prefetch geometry: thread t handles panel row t>>4, granules (t&15)+16j
  const int prow = tid >> 4;          // 0..31
  const int pgl = tid & 15;

  const int rt = wv >> 1, ct = wv & 1;     // wave's row-tile (0..3), col-tile (0..1)
  const int fr = lane & 15, fg = lane >> 4;
  float lmax = -3.4e38f;
  f32x4 k4[32];      // raw C (f16-rounded) until cmax round, then exp'd in place

#pragma unroll
  for (int p = 0; p < 32; p++) {
    // issue next panel's global loads early (latency hides under MFMA + barrier)
    uint4 pref[4];
    if (p < 31) {
      const char* srcrow = (const char*)Pf + (size_t)((p + 1) * 32 + prow) * 1024;
#pragma unroll
      for (int j = 0; j < 4; j++)
        pref[j] = *(const uint4*)(srcrow + (pgl + 16 * j) * 16);
    }

    f32x4 acc = {};
#pragma unroll
    for (int kk = 0; kk < 16; kk++) {
      int kg = kk * 4 + fg;
      int slot = (kg & ~7) | ((kg & 7) ^ (fr & 7));
      f16x8 av = *(const f16x8*)&X_lds[(rt * 16 + fr) * 512 + slot * 8];
      f16x8 bv = *(const f16x8*)&Pbuf[(ct * 16 + fr) * 512 + slot * 8];
      acc = __builtin_amdgcn_mfma_f32_16x16x32_f16(av, bv, acc, 0, 0, 0);
    }
    {  // tile epilogue: C/D layout col=lane&15, row=(lane>>4)*4+reg
      int colL = ct * 16 + fr;
      float pnc = pn_s[p * 32 + colL];
#pragma unroll
      for (int r = 0; r < 4; r++) {
        int rowL = rt * 16 + fg * 4 + r;
        float val = xn_s[rowL] + pnc - 2.0f * acc[r];
        lmax = fmaxf(lmax, val);   // f32 max before fp16 rounding (matches Ch path)
        t_lds[rowL * 36 + colL] = __half_as_ushort(__float2half(val));
      }
    }
    __syncthreads();   // B1: t_lds complete AND all Pbuf reads of panel p drained

    // commit prefetched panel p+1 into Pbuf (swizzled write = same involution as read)
    if (p < 31) {
#pragma unroll
      for (int j = 0; j < 4; j++) {
        int g = pgl + 16 * j;
        int slot = (g & ~7) | ((g & 7) ^ (prow & 7));
        *(uint4*)&Pbuf[prow * 512 + slot * 8] = pref[j];
      }
    }
    // extraction: cols [32p,32p+32) belong to lanes with lane>>5 == p&1,
    // k4 slot q=p>>3, e=(p>>1)&3 (all static under unroll)
    if ((lane >> 5) == (p & 1)) {
#pragma unroll
      for (int i = 0; i < 8; i++)
        k4[i * 4 + (p >> 3)][(p >> 1) & 3] =
            __half2float(__ushort_as_half(t_lds[(wv * 8 + i) * 36 + (lane & 31)]));
    }
    __syncthreads();   // B2: t_lds reusable + Pbuf write visible for next panel
  }

  // ---------------- global C-max round (flag value 1) ----------------
  lmax = wave_reduce_max(lmax);
  if (lane == 0) wred[wv] = lmax;
  __syncthreads();
  if (tid == 0) {
    float m = wred[0];
#pragma unroll
    for (int i = 1; i < 8; i++) m = fmaxf(m, wred[i]);
    atomicMax((int*)maxbits, __float_as_int(m));  // global max is positive
    __hip_atomic_store(&flags[(size_t)b * FLAG_STRIDE], 1u,
                       __ATOMIC_RELEASE, __HIP_MEMORY_SCOPE_AGENT);
  }
  if (tid < SINK_BLOCKS) {
    while (__hip_atomic_load(&flags[(size_t)tid * FLAG_STRIDE],
                             __ATOMIC_RELAXED, __HIP_MEMORY_SCOPE_AGENT) < 1u)
      __builtin_amdgcn_s_sleep(4);
  }
  __syncthreads();
  float factor;
  {
    float cmax = __uint_as_float(__hip_atomic_load(maxbits, __ATOMIC_RELAXED,
                                                   __HIP_MEMORY_SCOPE_AGENT));
    factor = -1.0f / ((cmax + 1e-8f) * EPS_F);
  }
#pragma unroll
  for (int j = 0; j < 32; j++)
#pragma unroll
    for (int e = 0; e < 4; e++)
      k4[j][e] = __expf(k4[j][e] * factor);

  // ---------------- phase 2: verified Sinkhorn loop (LDS aliases X region) ----------------
  float* v_lds = (float*)smem;                       // 4 KB
  float (*red)[K_PTS] = (float (*)[K_PTS])(smem + 4096);  // 8 x 4 KB
  v_lds[tid * 2 + 0] = 1.0f;
  v_lds[tid * 2 + 1] = 1.0f;
  __syncthreads();

  float su[8];
  for (int t = 0; t < ITERS; t++) {
    f32x4 vr4[4];
#pragma unroll
    for (int q = 0; q < 4; q++)
#pragma unroll
      for (int e = 0; e < 4; e++)
        vr4[q][e] = v_lds[(4 * q + e) * 64 + lane];

    float s[8];
#pragma unroll
    for (int i = 0; i < 8; i++) {
      f32x4 d = k4[i * 4 + 0] * vr4[0] + k4[i * 4 + 1] * vr4[1]
              + k4[i * 4 + 2] * vr4[2] + k4[i * 4 + 3] * vr4[3];
      s[i] = d[0] + d[1] + d[2] + d[3];
    }
    {
      const bool h32 = (lane & 32) != 0;
      float a[4];
#pragma unroll
      for (int i = 0; i < 4; i++) {
        float x = h32 ? s[i] : s[i + 4];
        float y = h32 ? s[i + 4] : s[i];
        a[i] = y + __shfl_xor(x, 32, 64);
      }
      const bool h16 = (lane & 16) != 0;
      float c[2];
#pragma unroll
      for (int i = 0; i < 2; i++) {
        float x = h16 ? a[i] : a[i + 2];
        float y = h16 ? a[i + 2] : a[i];
        c[i] = y + __shfl_xor(x, 16, 64);
      }
      const bool h8 = (lane & 8) != 0;
      float x = h8 ? c[0] : c[1];
      float y = h8 ? c[1] : c[0];
      float w = y + __shfl_xor(x, 8, 64);
      w += __shfl_xor(w, 4, 64);
      w += __shfl_xor(w, 2, 64);
      w += __shfl_xor(w, 1, 64);
      float ui_local = MU_F / (w + 1e-8f);
#pragma unroll
      for (int i = 0; i < 8; i++)
        su[i] = __uint_as_float(__builtin_amdgcn_readlane(__float_as_uint(ui_local), i * 8));
    }
    f32x4 ca4[4] = {};
#pragma unroll
    for (int i = 0; i < 8; i++)
#pragma unroll
      for (int q = 0; q < 4; q++)
        ca4[q] += su[i] * k4[i * 4 + q];

    __syncthreads();
#pragma unroll
    for (int q = 0; q < 4; q++)
#pragma unroll
      for (int e = 0; e < 4; e++)
        red[wv][(4 * q + e) * 64 + lane] = ca4[q][e];
    __syncthreads();
    {
      float s0 = 0.f, s1 = 0.f;
#pragma unroll
      for (int w8 = 0; w8 < 8; w8++) {
        float2 v2 = *(const float2*)&red[w8][tid * 2];
        s0 += v2.x; s1 += v2.y;
      }
      float* dst = accum + (size_t)(t + 1) * (NCOPY * K_PTS)
                 + (size_t)(b & (NCOPY - 1)) * K_PTS + tid * 2;
      atomicAdd(dst + 0, s0);
      atomicAdd(dst + 1, s1);
    }
    __syncthreads();
    if (tid == 0)
      __hip_atomic_store(&flags[(size_t)b * FLAG_STRIDE], (unsigned)(t + 2),
                         __ATOMIC_RELEASE, __HIP_MEMORY_SCOPE_AGENT);
    if (tid < SINK_BLOCKS) {
      while (__hip_atomic_load(&flags[(size_t)tid * FLAG_STRIDE],
                               __ATOMIC_RELAXED, __HIP_MEMORY_SCOPE_AGENT) < (unsigned)(t + 2))
        __builtin_amdgcn_s_sleep(4);
    }
    __syncthreads();
    {
      float* st = accum + (size_t)(t + 1) * (NCOPY * K_PTS);
      float s0 = 0.f, s1 = 0.f;
#pragma unroll
      for (int c = 0; c < NCOPY; c++) {  // agent-scope loads bypass stale caches (G16)
        s0 += __hip_atomic_load(st + (size_t)c * K_PTS + tid * 2 + 0,
                                __ATOMIC_RELAXED, __HIP_MEMORY_SCOPE_AGENT);
        s1 += __hip_atomic_load(st + (size_t)c * K_PTS + tid * 2 + 1,
                                __ATOMIC_RELAXED, __HIP_MEMORY_SCOPE_AGENT);
      }
      v_lds[tid * 2 + 0] = NU_F / (s0 + 1e-8f);
      v_lds[tid * 2 + 1] = NU_F / (s1 + 1e-8f);
    }
    __syncthreads();
  }

  // final: T = u*k*v from registers; loss = sum(T * (-eps*ln k)).
  float lsum = 0.f;
#pragma unroll
  for (int i = 0; i < 8; i++) {
    float* Trow = T + (size_t)(r0 + i) * K_PTS + lane;
#pragma unroll
    for (int q = 0; q < 4; q++) {
#pragma unroll
      for (int e = 0; e < 4; e++) {
        int c = (4 * q + e) * 64;
        float kk = k4[i * 4 + q][e];
        float tv = su[i] * kk * v_lds[c + lane];
        Trow[c] = tv;
        lsum += tv * (-EPS_F * __logf(kk));
      }
    }
  }
  lsum = wave_reduce_sum(lsum);
  __syncthreads();
  if (lane == 0) wred[wv] = lsum;
  __syncthreads();
  if (tid == 0) {
    float m = 0.f;
#pragma unroll
    for (int i = 0; i < 8; i++) m += wred[i];
    atomicAdd(loss, m);
  }
}

// ---------------------------------------------------------------- launcher
extern "C" void kernel_launch(void* const* d_in, const int* in_sizes, int n_in,
                              void* d_out, int out_size, void* d_ws, size_t ws_size,
                              hipStream_t stream) {
  const float* x = (const float*)d_in[0];
  const float* p = (const float*)d_in[1];
  float* T = (float*)d_out;
  float* loss = (float*)d_out + (size_t)N_PTS * K_PTS;

  // Pf16 + pn in d_out's upper half (clobbered only by final T writes,
  // which sit after 21 global flag barriers — all operand reads precede barrier 1)
  unsigned short* Pf = (unsigned short*)((char*)d_out + ((size_t)48 << 20));
  float* pn = (float*)((char*)d_out + ((size_t)49 << 20));

  char* wsb = (char*)d_ws;
  float* accum = (float*)wsb;
  unsigned int* flags = (unsigned int*)(wsb + WS_ACCUM_BYTES);
  unsigned int* maxbits = (unsigned int*)(wsb + WS_ACCUM_BYTES + WS_FLAGS_BYTES);

  init_kernel<<<(ACC_TOTAL + 255) / 256, 256, 0, stream>>>(accum, flags, maxbits, loss);
  convert_p_kernel<<<K_PTS / 4, 256, 0, stream>>>(p, Pf, pn);
  fused_kernel<<<SINK_BLOCKS, 512, 0, stream>>>(x, Pf, pn, maxbits, accum, flags, T, loss);
}